// Round 1
// 193.278 us; speedup vs baseline: 1.0203x; 1.0203x over previous
//
#include <hip/hip_runtime.h>
#include <hip/hip_bf16.h>
#include <math.h>

// Problem constants (all fp32 on the wire)
#define B_   4
#define T_   2048
#define DM   1024      // d_model
#define DH   256       // d_hidden
#define M_   (B_*T_)   // 8192 rows

typedef __bf16 bf16;
typedef __attribute__((ext_vector_type(8))) __bf16 bf16x8;
typedef __attribute__((ext_vector_type(4))) float  f32x4;

__device__ inline float sigmoidf_(float x) { return 1.0f / (1.0f + __expf(-x)); }

// T2-style LDS XOR swizzle: rows are 64 bf16 = 8 chunks of 16B.
// chunk' = chunk ^ (row & 7). Bijective per row; same formula on write & read.
__device__ inline int swz8(int r, int c) { return (((c >> 3) ^ (r & 7)) << 3); }

// ---- fused: transpose+convert 4 weights, and zero numb/denb ----------------
__global__ void transpose_cvt_all(const float* __restrict__ Wq, const float* __restrict__ Wk,
                                  const float* __restrict__ Wv, const float* __restrict__ Wo,
                                  bf16* __restrict__ Wq_t, bf16* __restrict__ Wk_t,
                                  bf16* __restrict__ Wv_t, bf16* __restrict__ Wo_t,
                                  float* __restrict__ nd)
{
    const int bid = blockIdx.x;
    if (bid >= 1024) {                      // zero numb+denb (contiguous 2048 f32)
        nd[(bid - 1024) * 256 + threadIdx.x] = 0.f;
        return;
    }
    __shared__ float tile[32][33];
    const int w = bid >> 8, t = bid & 255;
    const float* in; bf16* out; int R, C, sh;
    if      (w == 0) { in = Wq; out = Wq_t; R = DM; C = DH; sh = 3; }
    else if (w == 1) { in = Wk; out = Wk_t; R = DM; C = DH; sh = 3; }
    else if (w == 2) { in = Wv; out = Wv_t; R = DM; C = DH; sh = 3; }
    else             { in = Wo; out = Wo_t; R = DH; C = DM; sh = 5; }
    const int r0 = (t >> sh) * 32, c0 = (t & ((1 << sh) - 1)) * 32;
    const int tx = threadIdx.x & 31, ty = threadIdx.x >> 5;
    #pragma unroll
    for (int i = ty; i < 32; i += 8)
        tile[i][tx] = in[(long)(r0 + i) * C + c0 + tx];
    __syncthreads();
    #pragma unroll
    for (int i = ty; i < 32; i += 8)
        out[(long)(c0 + i) * R + r0 + tx] = (bf16)tile[tx][i];
}

// ---- projections: C_z = A_z @ W_z -> bf16 [M_][DH] in ws -------------------
// Tile 64x128, BK=64, 512 thr (8 waves = 2m x 4n).
// LDS double-buffer (1 barrier/slab) + ring-2 register prefetch + XOR swizzle
// (48 KB LDS -> 3 blocks/CU) + XCD-aware tile swizzle (A-panel pairs on one XCD).
__global__ __launch_bounds__(512, 6)
void gemm_proj(const float* __restrict__ qin, const float* __restrict__ kin,
               const float* __restrict__ vin,
               const bf16* __restrict__ Wq_t, const bf16* __restrict__ Wk_t,
               const bf16* __restrict__ Wv_t,
               bf16* __restrict__ Yb, bf16* __restrict__ Kb, bf16* __restrict__ Vb)
{
    __shared__ __align__(16) bf16 As[2][64][64];
    __shared__ __align__(16) bf16 Bs[2][128][64];

    const int z = blockIdx.z;
    const float* A  = (z == 0) ? qin  : (z == 1) ? kin  : vin;
    const bf16*  Wt = (z == 0) ? Wq_t : (z == 1) ? Wk_t : Wv_t;
    bf16*        C  = (z == 0) ? Yb   : (z == 1) ? Kb   : Vb;

    // 256 blocks/z; HW round-robins consecutive blocks over 8 XCDs -> give
    // each XCD a contiguous tile chunk so n0={0,128} pairs share an A panel.
    const int bid  = blockIdx.x;                  // 0..255
    const int tile = (bid & 7) * 32 + (bid >> 3); // bijective (256 % 8 == 0)
    const int m0 = (tile >> 1) * 64;
    const int n0 = (tile & 1) * 128;

    const int tid = threadIdx.x, lane = tid & 63, wave = tid >> 6;
    const int wr = wave >> 2, wc = wave & 3;   // wave: 32m x 32n
    const int q4 = lane >> 4, l16 = lane & 15;

    f32x4 acc[2][2] = {};
    const int ar = tid >> 3, ac8 = (tid & 7) * 8;    // A: 64r x 64 fp32
    const int br = tid >> 2, bc16 = (tid & 3) * 16;  // B: 128r x 64 bf16

    const float* aBase = &A[(long)(m0 + ar) * DM + ac8];
    const bf16*  bBase = &Wt[(long)(n0 + br) * DM + bc16];

    f32x4  pa0[2], pa1[2];
    bf16x8 pb0[2], pb1[2];
    #pragma unroll
    for (int p = 0; p < 2; ++p) {               // preload slabs 0,1
        const float* ap = aBase + p * 64;
        pa0[p] = *(const f32x4*)ap; pa1[p] = *(const f32x4*)(ap + 4);
        const bf16* bp = bBase + p * 64;
        pb0[p] = *(const bf16x8*)bp; pb1[p] = *(const bf16x8*)(bp + 8);
    }
    {   // stage slab 0 -> buf 0
        bf16x8 o;
        #pragma unroll
        for (int e = 0; e < 4; ++e) { o[e] = (bf16)pa0[0][e]; o[4 + e] = (bf16)pa1[0][e]; }
        *(bf16x8*)&As[0][ar][swz8(ar, ac8)]      = o;
        *(bf16x8*)&Bs[0][br][swz8(br, bc16)]     = pb0[0];
        *(bf16x8*)&Bs[0][br][swz8(br, bc16 + 8)] = pb1[0];
    }
    __syncthreads();

    #pragma unroll
    for (int s = 0; s < 16; ++s) {              // 16 slabs of BK=64
        const int cs = s & 1;                   // buffer/slot of slab s
        const int ns = cs ^ 1;                  // buffer/slot of slab s+1
        if (s + 2 < 16) {                       // refill slot cs with slab s+2
            const float* ap = aBase + (s + 2) * 64;
            pa0[cs] = *(const f32x4*)ap; pa1[cs] = *(const f32x4*)(ap + 4);
            const bf16* bp = bBase + (s + 2) * 64;
            pb0[cs] = *(const bf16x8*)bp; pb1[cs] = *(const bf16x8*)(bp + 8);
        }
        if (s + 1 < 16) {                       // stage slab s+1 -> other buffer
            bf16x8 o;
            #pragma unroll
            for (int e = 0; e < 4; ++e) { o[e] = (bf16)pa0[ns][e]; o[4 + e] = (bf16)pa1[ns][e]; }
            *(bf16x8*)&As[ns][ar][swz8(ar, ac8)]      = o;
            *(bf16x8*)&Bs[ns][br][swz8(br, bc16)]     = pb0[ns];
            *(bf16x8*)&Bs[ns][br][swz8(br, bc16 + 8)] = pb1[ns];
        }
        #pragma unroll
        for (int kk = 0; kk < 64; kk += 32) {
            const int ra = wr * 32 + l16, rb = wc * 32 + l16;
            bf16x8 a0 = *(const bf16x8*)&As[cs][ra     ][swz8(ra,      kk + q4 * 8)];
            bf16x8 a1 = *(const bf16x8*)&As[cs][ra + 16][swz8(ra + 16, kk + q4 * 8)];
            bf16x8 b0 = *(const bf16x8*)&Bs[cs][rb     ][swz8(rb,      kk + q4 * 8)];
            bf16x8 b1 = *(const bf16x8*)&Bs[cs][rb + 16][swz8(rb + 16, kk + q4 * 8)];
            acc[0][0] = __builtin_amdgcn_mfma_f32_16x16x32_bf16(a0, b0, acc[0][0], 0, 0, 0);
            acc[0][1] = __builtin_amdgcn_mfma_f32_16x16x32_bf16(a0, b1, acc[0][1], 0, 0, 0);
            acc[1][0] = __builtin_amdgcn_mfma_f32_16x16x32_bf16(a1, b0, acc[1][0], 0, 0, 0);
            acc[1][1] = __builtin_amdgcn_mfma_f32_16x16x32_bf16(a1, b1, acc[1][1], 0, 0, 0);
        }
        __syncthreads();
    }
    // C/D layout: col = lane&15, row = (lane>>4)*4 + reg. z==0 -> sigmoid.
    #pragma unroll
    for (int i = 0; i < 2; ++i)
        #pragma unroll
        for (int j = 0; j < 2; ++j)
            #pragma unroll
            for (int r = 0; r < 4; ++r) {
                int gm = m0 + wr * 32 + i * 16 + q4 * 4 + r;
                int gn = n0 + wc * 32 + j * 16 + l16;
                float v = acc[i][j][r];
                C[(long)gm * DH + gn] = (bf16)((z == 0) ? sigmoidf_(v) : v);
            }
}

// ---- exp-weighted reduction over j ----------------------------------------
// 256 blocks x 256 thr; thread = (d-group of 8, one j). bf16x8 loads (16B/lane),
// shfl_xor(32) pairs jj, 32 KB LDS tree over 4 waves, then atomics.
__global__ void reduce_kv(const bf16* __restrict__ Kb, const bf16* __restrict__ Vb,
                          float* __restrict__ numb, float* __restrict__ denb)
{
    __shared__ float red[2][4][B_][DH];     // [arr][wave][b][d] = 32 KB
    const int tid = threadIdx.x;
    const int g = tid & 31, jj = tid >> 5;  // 32 d-groups x 8 j
    const int d8 = g * 8;
    const int j = blockIdx.x * 8 + jj;

    bf16x8 kx[B_], vx[B_];
    #pragma unroll
    for (int b = 0; b < B_; ++b) {
        kx[b] = *(const bf16x8*)&Kb[((long)b * T_ + j) * DH + d8];
        vx[b] = *(const bf16x8*)&Vb[((long)b * T_ + j) * DH + d8];
    }
    float sn[B_][8], sd[B_][8];
    #pragma unroll
    for (int e = 0; e < 8; ++e) {
        float k0 = (float)kx[0][e], k1 = (float)kx[1][e];
        float k2 = (float)kx[2][e], k3 = (float)kx[3][e];
        float mx = fmaxf(fmaxf(k0, k1), fmaxf(k2, k3));
        float e0 = __expf(k0 - mx), e1 = __expf(k1 - mx);
        float e2 = __expf(k2 - mx), e3 = __expf(k3 - mx);
        sn[0][e] = e0 * (float)vx[0][e]; sd[0][e] = e0;
        sn[1][e] = e1 * (float)vx[1][e]; sd[1][e] = e1;
        sn[2][e] = e2 * (float)vx[2][e]; sd[2][e] = e2;
        sn[3][e] = e3 * (float)vx[3][e]; sd[3][e] = e3;
    }
    // combine jj with jj^1 (lanes l <-> l+32 within the wave)
    #pragma unroll
    for (int b = 0; b < B_; ++b)
        #pragma unroll
        for (int e = 0; e < 8; ++e) {
            sn[b][e] += __shfl_xor(sn[b][e], 32);
            sd[b][e] += __shfl_xor(sd[b][e], 32);
        }
    const int w = tid >> 6;
    if ((tid & 32) == 0) {                  // jj even holds the pair sum
        #pragma unroll
        for (int b = 0; b < B_; ++b)
            #pragma unroll
            for (int e = 0; e < 8; ++e) {
                red[0][w][b][d8 + e] = sn[b][e];
                red[1][w][b][d8 + e] = sd[b][e];
            }
    }
    __syncthreads();
    #pragma unroll
    for (int o = tid; o < 2 * B_ * DH; o += 256) {
        const int arr = o >> 10, b = (o >> 8) & 3, d = o & 255;
        float s = red[arr][0][b][d] + red[arr][1][b][d]
                + red[arr][2][b][d] + red[arr][3][b][d];
        float* dst = (o < 1024) ? &numb[o] : &denb[o - 1024];
        atomicAdd(dst, s);
    }
}

// ---- output GEMM: out = (Yb * rv[b]) @ Wo, fp32 out ------------------------
// Yb already holds sigmoid(Q). Same dbuf/1-barrier/swizzle structure, K=256.
__global__ __launch_bounds__(512, 6)
void gemm_out(const bf16* __restrict__ Yb, const bf16* __restrict__ Wo_t,
              const float* __restrict__ numb, const float* __restrict__ denb,
              float* __restrict__ out)
{
    __shared__ __align__(16) bf16 As[2][64][64];
    __shared__ __align__(16) bf16 Bs[2][128][64];
    __shared__ float rv_s[DH];

    // 1024 blocks; per-XCD contiguous chunk so the 8 n-blocks of an A panel
    // (Yb rows, reused 8x) stay on one XCD's L2.
    const int bid  = blockIdx.x;                   // 0..1023
    const int tile = (bid & 7) * 128 + (bid >> 3); // bijective (1024 % 8 == 0)
    const int m0 = (tile >> 3) * 64;
    const int n0 = (tile & 7) * 128;
    const int b  = m0 >> 11;                       // batch = m0/2048

    const int tid = threadIdx.x, lane = tid & 63, wave = tid >> 6;
    const int wr = wave >> 2, wc = wave & 3;
    const int q4 = lane >> 4, l16 = lane & 15;

    if (tid < DH) rv_s[tid] = numb[b * DH + tid] / denb[b * DH + tid];

    f32x4 acc[2][2] = {};
    const int ar = tid >> 3, ac8 = (tid & 7) * 8;
    const int br = tid >> 2, bc16 = (tid & 3) * 16;

    const bf16* aBase = &Yb[(long)(m0 + ar) * DH + ac8];
    const bf16* bBase = &Wo_t[(long)(n0 + br) * DH + bc16];

    bf16x8 pq[2], pb0[2], pb1[2];
    #pragma unroll
    for (int p = 0; p < 2; ++p) {
        pq[p]  = *(const bf16x8*)(aBase + p * 64);
        const bf16* wp = bBase + p * 64;
        pb0[p] = *(const bf16x8*)wp; pb1[p] = *(const bf16x8*)(wp + 8);
    }
    __syncthreads();        // rv_s ready before staging uses it
    {   // stage slab 0 -> buf 0
        bf16x8 o;
        #pragma unroll
        for (int e = 0; e < 8; ++e)
            o[e] = (bf16)((float)pq[0][e] * rv_s[ac8 + e]);
        *(bf16x8*)&As[0][ar][swz8(ar, ac8)]      = o;
        *(bf16x8*)&Bs[0][br][swz8(br, bc16)]     = pb0[0];
        *(bf16x8*)&Bs[0][br][swz8(br, bc16 + 8)] = pb1[0];
    }
    __syncthreads();

    #pragma unroll
    for (int s = 0; s < 4; ++s) {               // 4 slabs of BK=64
        const int cs = s & 1, ns = cs ^ 1;
        if (s + 2 < 4) {
            pq[cs]  = *(const bf16x8*)(aBase + (s + 2) * 64);
            const bf16* wp = bBase + (s + 2) * 64;
            pb0[cs] = *(const bf16x8*)wp; pb1[cs] = *(const bf16x8*)(wp + 8);
        }
        if (s + 1 < 4) {
            bf16x8 o;
            #pragma unroll
            for (int e = 0; e < 8; ++e)
                o[e] = (bf16)((float)pq[ns][e] * rv_s[(s + 1) * 64 + ac8 + e]);
            *(bf16x8*)&As[ns][ar][swz8(ar, ac8)]      = o;
            *(bf16x8*)&Bs[ns][br][swz8(br, bc16)]     = pb0[ns];
            *(bf16x8*)&Bs[ns][br][swz8(br, bc16 + 8)] = pb1[ns];
        }
        #pragma unroll
        for (int kk = 0; kk < 64; kk += 32) {
            const int ra = wr * 32 + l16, rb = wc * 32 + l16;
            bf16x8 a0 = *(const bf16x8*)&As[cs][ra     ][swz8(ra,      kk + q4 * 8)];
            bf16x8 a1 = *(const bf16x8*)&As[cs][ra + 16][swz8(ra + 16, kk + q4 * 8)];
            bf16x8 b0 = *(const bf16x8*)&Bs[cs][rb     ][swz8(rb,      kk + q4 * 8)];
            bf16x8 b1 = *(const bf16x8*)&Bs[cs][rb + 16][swz8(rb + 16, kk + q4 * 8)];
            acc[0][0] = __builtin_amdgcn_mfma_f32_16x16x32_bf16(a0, b0, acc[0][0], 0, 0, 0);
            acc[0][1] = __builtin_amdgcn_mfma_f32_16x16x32_bf16(a0, b1, acc[0][1], 0, 0, 0);
            acc[1][0] = __builtin_amdgcn_mfma_f32_16x16x32_bf16(a1, b0, acc[1][0], 0, 0, 0);
            acc[1][1] = __builtin_amdgcn_mfma_f32_16x16x32_bf16(a1, b1, acc[1][1], 0, 0, 0);
        }
        __syncthreads();
    }
    #pragma unroll
    for (int i = 0; i < 2; ++i)
        #pragma unroll
        for (int j = 0; j < 2; ++j)
            #pragma unroll
            for (int r = 0; r < 4; ++r) {
                int gm = m0 + wr * 32 + i * 16 + q4 * 4 + r;
                int gn = n0 + wc * 32 + j * 16 + l16;
                out[(long)gm * DM + gn] = acc[i][j][r];
            }
}

// ---------------- launch ----------------
extern "C" void kernel_launch(void* const* d_in, const int* in_sizes, int n_in,
                              void* d_out, int out_size, void* d_ws, size_t ws_size,
                              hipStream_t stream)
{
    const float* q  = (const float*)d_in[0];
    const float* k  = (const float*)d_in[1];
    const float* v  = (const float*)d_in[2];
    const float* Wq = (const float*)d_in[3];
    const float* Wk = (const float*)d_in[4];
    const float* Wv = (const float*)d_in[5];
    const float* Wo = (const float*)d_in[6];
    // d_in[7] = W_bias: provably unused (exp_pos_bias == ones)
    float* out = (float*)d_out;

    // Workspace: 14.02 MB
    char* ws = (char*)d_ws;
    bf16* Yb    = (bf16*)ws;  ws += (size_t)M_ * DH * sizeof(bf16);   // sigmoid(Q), 4 MB
    bf16* Kb    = (bf16*)ws;  ws += (size_t)M_ * DH * sizeof(bf16);   // 4 MB
    bf16* Vb    = (bf16*)ws;  ws += (size_t)M_ * DH * sizeof(bf16);   // 4 MB
    bf16* Wq_t  = (bf16*)ws;  ws += (size_t)DM * DH * sizeof(bf16);   // 0.5 MB
    bf16* Wk_t  = (bf16*)ws;  ws += (size_t)DM * DH * sizeof(bf16);
    bf16* Wv_t  = (bf16*)ws;  ws += (size_t)DM * DH * sizeof(bf16);
    bf16* Wo_t  = (bf16*)ws;  ws += (size_t)DM * DH * sizeof(bf16);
    float* numb = (float*)ws; ws += (size_t)B_ * DH * sizeof(float);  // 4 KB
    float* denb = (float*)ws; ws += (size_t)B_ * DH * sizeof(float);  // contiguous after numb

    transpose_cvt_all<<<1032, 256, 0, stream>>>(Wq, Wk, Wv, Wo,
                                                Wq_t, Wk_t, Wv_t, Wo_t, numb);

    gemm_proj<<<dim3(256, 1, 3), 512, 0, stream>>>(q, k, v, Wq_t, Wk_t, Wv_t,
                                                   Yb, Kb, Vb);
    reduce_kv<<<256, 256, 0, stream>>>(Kb, Vb, numb, denb);
    gemm_out<<<1024, 512, 0, stream>>>(Yb, Wo_t, numb, denb, out);
}